// Round 7
// baseline (15.024 us; speedup 1.0000x reference)
//
#include <hip/hip_runtime.h>
#include <hip/hip_bf16.h>
#include <string.h>

// out[n][c] = -sum_f (x[n][f]-m[c][f])^2 = 2*x.m - |x|^2 - |m|^2
// N=2048, C=512, F=512, fp32 in/out.
//
// Kernel 1 (prep): fp32 -> bf16 once over the 5MB of unique data, rows written
//   PRE-SWIZZLED (16B slot s of row r stored at position s^(r&7)) so the GEMM
//   can stage tiles with linear global_load_lds. Exact fp32 row norms.
// Kernel 2 (nsq_gemm): grid=256 (1 block/CU), 512 thr (8 waves, 2/SIMD).
//   64x64 tile, full K=512 in LDS (128KB). Staging = 16 global_load_lds
//   width-16 per thread (pure async copy, no VALU). Split-K: waves 0-3 own
//   the four 32x32 quadrants for K=0..255, waves 4-7 for K=256..511;
//   partials combined via stride-17-padded LDS. Epilogue fuses norms.

#define N_ROWS 2048
#define C_ROWS 512
#define F_DIM  512

typedef __attribute__((ext_vector_type(8))) short short8;
typedef __attribute__((ext_vector_type(4))) float f32x4;

static __device__ __forceinline__ unsigned pk_bf16(float lo, float hi) {
    __hip_bfloat162 h = __float22bfloat162_rn(make_float2(lo, hi));
    unsigned u;
    memcpy(&u, &h, 4);  // register move; h comes from v_cvt_pk_bf16_f32
    return u;
}

// One wave per row (4 waves/block, grid 640). Lane covers 8 contiguous
// floats -> one 16B write at swizzled slot lane^(row&7). Full-wave shfl
// reduction for the fp32 norm.
__global__ __launch_bounds__(256) void prep_kernel(
        const float* __restrict__ x, const float* __restrict__ means,
        short* __restrict__ xb, short* __restrict__ mb,
        float* __restrict__ xnorm, float* __restrict__ mnorm) {
    const int w    = threadIdx.x >> 6;
    const int lane = threadIdx.x & 63;
    const int row  = blockIdx.x * 4 + w;  // 0..2559

    const float* src;
    short* dst;
    float* nrm;
    int rk;  // swizzle key = (row within 64-aligned tile) & 7 == global row & 7
    if (row < N_ROWS) {
        src = x + (size_t)row * F_DIM;
        dst = xb + (size_t)row * F_DIM;
        nrm = xnorm + row;
        rk  = row & 7;
    } else {
        const int r = row - N_ROWS;
        src = means + (size_t)r * F_DIM;
        dst = mb + (size_t)r * F_DIM;
        nrm = mnorm + r;
        rk  = r & 7;
    }

    float4 v0 = *(const float4*)(src + lane * 8);
    float4 v1 = *(const float4*)(src + lane * 8 + 4);
    float vv[8] = {v0.x, v0.y, v0.z, v0.w, v1.x, v1.y, v1.z, v1.w};

    float ss = 0.f;
#pragma unroll
    for (int j = 0; j < 8; j++) ss += vv[j] * vv[j];

    int4 o;
    o.x = (int)pk_bf16(vv[0], vv[1]);
    o.y = (int)pk_bf16(vv[2], vv[3]);
    o.z = (int)pk_bf16(vv[4], vv[5]);
    o.w = (int)pk_bf16(vv[6], vv[7]);
    // pre-swizzled position: slot lane -> lane ^ rk (16B slots)
    *(int4*)(dst + ((lane ^ rk) << 3)) = o;

#pragma unroll
    for (int off = 32; off > 0; off >>= 1) ss += __shfl_xor(ss, off);
    if (lane == 0) *nrm = ss;
}

__global__ __launch_bounds__(512) void nsq_gemm(
        const short* __restrict__ xb, const short* __restrict__ mb,
        const float* __restrict__ xnorm, const float* __restrict__ mnorm,
        float* __restrict__ out) {
    // Tiles arrive already swizzled: value of logical slot s of row r sits at
    // position s^(r&7). Staging is a LINEAR 64KB copy per tile.
    __shared__ __align__(16) short As[64 * 512];
    __shared__ __align__(16) short Bs[64 * 512];
    __shared__ float xn_s[64], mn_s[64];

    // XCD (d&7) owns 4 consecutive row-tiles: per-XCD L2 set = 256KB of xb +
    // 512KB of mb, resident across replays.
    const int d  = blockIdx.x;                     // 0..255
    const int by = (d & 7) * 4 + ((d >> 3) & 3);   // 0..31
    const int bx = d >> 5;                         // 0..7
    const int rowBase = by * 64, colBase = bx * 64;

    const int t    = threadIdx.x;
    const int w    = t >> 6;      // 0..7
    const int lane = t & 63;

    // ---------------- Phase 1: async tile staging (no VALU) --------------
    const short* ga = xb + (size_t)rowBase * F_DIM;  // contiguous 64KB tile
    const short* gb = mb + (size_t)colBase * F_DIM;
#pragma unroll
    for (int i = 0; i < 8; i++) {
        // chunk (i*512 + t): 16B. LDS dest = wave-uniform base; HW adds lane*16.
        const short* srcA = ga + ((size_t)(i * 512 + t) << 3);
        const short* srcB = gb + ((size_t)(i * 512 + t) << 3);
        short* la = As + i * 4096 + w * 512;
        short* lb = Bs + i * 4096 + w * 512;
        __builtin_amdgcn_global_load_lds(
            (const __attribute__((address_space(1))) void*)srcA,
            (__attribute__((address_space(3))) void*)la, 16, 0, 0);
        __builtin_amdgcn_global_load_lds(
            (const __attribute__((address_space(1))) void*)srcB,
            (__attribute__((address_space(3))) void*)lb, 16, 0, 0);
    }
    if (t < 64)       xn_s[t]      = xnorm[rowBase + t];
    else if (t < 128) mn_s[t - 64] = mnorm[colBase + (t - 64)];
    __syncthreads();  // implicit vmcnt(0)+lgkmcnt(0): tiles + norms ready

    // ---------------- Phase 2: MFMA, split-K across wave groups ----------
    const int quad = w & 3;       // output quadrant
    const int kh   = w >> 2;      // K-half
    const int wr   = (quad >> 1) * 32;
    const int wc   = (quad & 1) * 32;

    f32x4 acc[2][2];
#pragma unroll
    for (int mi = 0; mi < 2; mi++)
#pragma unroll
        for (int ni = 0; ni < 2; ni++)
            acc[mi][ni] = (f32x4){0.f, 0.f, 0.f, 0.f};

#pragma unroll
    for (int j = 0; j < 8; j++) {
        const int kk   = kh * 8 + j;
        const int slot = kk * 4 + (lane >> 4);
        short8 a[2], b[2];
#pragma unroll
        for (int mi = 0; mi < 2; mi++) {
            const int r = wr + mi * 16 + (lane & 15);
            a[mi] = *(const short8*)(As + r * F_DIM + ((slot ^ (r & 7)) << 3));
        }
#pragma unroll
        for (int ni = 0; ni < 2; ni++) {
            const int r = wc + ni * 16 + (lane & 15);
            b[ni] = *(const short8*)(Bs + r * F_DIM + ((slot ^ (r & 7)) << 3));
        }
#pragma unroll
        for (int mi = 0; mi < 2; mi++)
#pragma unroll
            for (int ni = 0; ni < 2; ni++)
                acc[mi][ni] = __builtin_amdgcn_mfma_f32_16x16x32_bf16(
                    a[mi], b[ni], acc[mi][ni], 0, 0, 0);
    }

    // ---------------- Split-K combine via padded LDS (reuse As) ----------
    __syncthreads();  // all ds_reads of As/Bs done before aliasing As
    float* red = (float*)As;
    if (kh == 1) {
#pragma unroll
        for (int mi = 0; mi < 2; mi++)
#pragma unroll
            for (int ni = 0; ni < 2; ni++)
#pragma unroll
                for (int j = 0; j < 4; j++)
                    red[quad * 1088 + lane * 17 + mi * 8 + ni * 4 + j] =
                        acc[mi][ni][j];
    }
    __syncthreads();
    if (kh == 0) {
#pragma unroll
        for (int mi = 0; mi < 2; mi++)
#pragma unroll
            for (int ni = 0; ni < 2; ni++)
#pragma unroll
                for (int j = 0; j < 4; j++)
                    acc[mi][ni][j] +=
                        red[quad * 1088 + lane * 17 + mi * 8 + ni * 4 + j];

        // ---------------- Epilogue: out = 2*acc - |x|^2 - |m|^2 ----------
        // C/D layout: col = lane&15, row = (lane>>4)*4 + j.
        float xn[2][4];
#pragma unroll
        for (int mi = 0; mi < 2; mi++)
#pragma unroll
            for (int j = 0; j < 4; j++)
                xn[mi][j] = xn_s[wr + mi * 16 + (lane >> 4) * 4 + j];

#pragma unroll
        for (int ni = 0; ni < 2; ni++) {
            const int cl = wc + ni * 16 + (lane & 15);
            const int c  = colBase + cl;
            const float mn = mn_s[cl];
#pragma unroll
            for (int mi = 0; mi < 2; mi++) {
                const int rbase = rowBase + wr + mi * 16 + (lane >> 4) * 4;
#pragma unroll
                for (int j = 0; j < 4; j++)
                    out[(size_t)(rbase + j) * C_ROWS + c] =
                        2.0f * acc[mi][ni][j] - xn[mi][j] - mn;
            }
        }
    }
}

// Safety net if workspace is unexpectedly small.
__global__ __launch_bounds__(256) void fallback_kernel(
        const float* __restrict__ x, const float* __restrict__ means,
        float* __restrict__ out) {
    __shared__ float xrow[F_DIM];
    const int n = blockIdx.x;
    const int c = blockIdx.y * 256 + threadIdx.x;
    for (int f = threadIdx.x; f < F_DIM; f += 256) xrow[f] = x[(size_t)n * F_DIM + f];
    __syncthreads();
    const float* m = means + (size_t)c * F_DIM;
    float s = 0.f;
    for (int f = 0; f < F_DIM; f++) {
        float d = xrow[f] - m[f];
        s += d * d;
    }
    out[(size_t)n * C_ROWS + c] = -s;
}

extern "C" void kernel_launch(void* const* d_in, const int* in_sizes, int n_in,
                              void* d_out, int out_size, void* d_ws, size_t ws_size,
                              hipStream_t stream) {
    const float* x     = (const float*)d_in[0];
    const float* means = (const float*)d_in[1];
    float* out = (float*)d_out;

    const size_t need = (size_t)N_ROWS * F_DIM * 2 + (size_t)C_ROWS * F_DIM * 2 +
                        (size_t)(N_ROWS + C_ROWS) * 4;
    if (ws_size >= need) {
        short* xb = (short*)d_ws;
        short* mb = xb + (size_t)N_ROWS * F_DIM;
        float* xnorm = (float*)(mb + (size_t)C_ROWS * F_DIM);
        float* mnorm = xnorm + N_ROWS;

        prep_kernel<<<(N_ROWS + C_ROWS) / 4, 256, 0, stream>>>(
            x, means, xb, mb, xnorm, mnorm);
        nsq_gemm<<<256, 512, 0, stream>>>(xb, mb, xnorm, mnorm, out);
    } else {
        dim3 grid(N_ROWS, C_ROWS / 256);
        fallback_kernel<<<grid, 256, 0, stream>>>(x, means, out);
    }
}

// Round 8
// 11.622 us; speedup vs baseline: 1.2928x; 1.2928x over previous
//
#include <hip/hip_runtime.h>
#include <hip/hip_bf16.h>
#include <string.h>

// out[n][c] = -sum_f (x[n][f]-m[c][f])^2 = 2*x.m - |x|^2 - |m|^2
// N=2048, C=512, F=512, fp32 in/out.
//
// Single fused kernel, grid=256 (1 block/CU), 1024 threads (16 waves ->
// 4 waves/SIMD). 64x64 output tile, full K=512 in LDS (A+B 128KB bf16,
// 16B slots XOR-swizzled by row&7 on both write and read sides).
// Phase 1: waves 0-7 stage+convert A (x rows), waves 8-15 B (means rows);
//   hardware v_cvt_pk_bf16_f32 (RNE) conversion; exact fp32 norms -> LDS.
// Phase 2: 4-way split-K (wave w: quadrant w&3, K-quarter w>>2).
// Combine: 3 partial groups written as b128 to As (aliased), slot-XOR
//   layout at the LDS structural throughput floor; group 0 accumulates.
// Epilogue fuses 2*acc - |x|^2 - |m|^2.

#define F_DIM  512
#define C_ROWS 512

typedef __attribute__((ext_vector_type(8))) short short8;
typedef __attribute__((ext_vector_type(4))) float f32x4;

static __device__ __forceinline__ unsigned pk_bf16(float lo, float hi) {
    __hip_bfloat162 h = __float22bfloat162_rn(make_float2(lo, hi));
    unsigned u;
    memcpy(&u, &h, 4);  // register move; h comes from v_cvt_pk_bf16_f32
    return u;
}

__global__ __launch_bounds__(1024) void ncm_fused(
        const float* __restrict__ x, const float* __restrict__ means,
        float* __restrict__ out) {
    __shared__ __align__(16) short As[64 * 512];
    __shared__ __align__(16) short Bs[64 * 512];
    __shared__ float xn_s[64], mn_s[64];

    // XCD (d&7) owns 4 consecutive row-tiles: per-XCD L2 working set =
    // 512KB of x + 2MB of means, L2-resident across replays.
    const int d  = blockIdx.x;                     // 0..255
    const int by = (d & 7) * 4 + ((d >> 3) & 3);   // 0..31
    const int bx = d >> 5;                         // 0..7
    const int rowBase = by * 64, colBase = bx * 64;

    const int t    = threadIdx.x;
    const int w    = t >> 6;      // 0..15
    const int lane = t & 63;
    const int qr   = lane >> 4;   // quarter-wave row offset
    const int ql   = lane & 15;   // lane within quarter-wave

    // ---------------- Phase 1: stage + convert + norms ----------------
    // Waves 0-7: A-half (x rows); waves 8-15: B-half (means rows).
    // Each wave: 8 rows; quarter-wave owns a row per i; lane covers 8
    // contiguous floats per (i,ph) -> one swizzled 16B LDS write.
    {
        const int half  = w >> 3;
        const int wrow8 = (w & 7) * 8;
        const float* src = (half == 0) ? x + (size_t)rowBase * F_DIM
                                       : means + (size_t)colBase * F_DIM;
        short* dst = (half == 0) ? As : Bs;
        float* nrm = (half == 0) ? xn_s : mn_s;

#pragma unroll
        for (int i = 0; i < 2; i++) {
            const int r = wrow8 + i * 4 + qr;
            const float* rowp = src + (size_t)r * F_DIM;
            // batch this row's 8 float4 loads (32 VGPR), then convert
            float4 va[4][2];
#pragma unroll
            for (int ph = 0; ph < 4; ph++) {
                const float* p = rowp + ph * 128 + ql * 8;
                va[ph][0] = *(const float4*)p;
                va[ph][1] = *(const float4*)(p + 4);
            }
            float ss = 0.f;
#pragma unroll
            for (int ph = 0; ph < 4; ph++) {
                float vv[8] = {va[ph][0].x, va[ph][0].y, va[ph][0].z, va[ph][0].w,
                               va[ph][1].x, va[ph][1].y, va[ph][1].z, va[ph][1].w};
#pragma unroll
                for (int j = 0; j < 8; j++) ss += vv[j] * vv[j];
                int4 o;  // 4x v_cvt_pk_bf16_f32 (hardware RNE)
                o.x = (int)pk_bf16(vv[0], vv[1]);
                o.y = (int)pk_bf16(vv[2], vv[3]);
                o.z = (int)pk_bf16(vv[4], vv[5]);
                o.w = (int)pk_bf16(vv[6], vv[7]);
                const int slot = ph * 16 + ql;
                *(int4*)(dst + r * F_DIM + ((slot ^ (r & 7)) << 3)) = o;
            }
            // quarter-wave reduction (within 16 lanes) -> exact fp32 norm
            ss += __shfl_xor(ss, 1);
            ss += __shfl_xor(ss, 2);
            ss += __shfl_xor(ss, 4);
            ss += __shfl_xor(ss, 8);
            if (ql == 0) nrm[r] = ss;
        }
    }
    __syncthreads();

    // ---------------- Phase 2: MFMA, 4-way split-K ----------------
    const int quad = w & 3;       // output quadrant (32x32)
    const int kh   = w >> 2;      // K-quarter: kh*128 .. +127
    const int wr   = (quad >> 1) * 32;
    const int wc   = (quad & 1) * 32;

    f32x4 acc[2][2];
#pragma unroll
    for (int mi = 0; mi < 2; mi++)
#pragma unroll
        for (int ni = 0; ni < 2; ni++)
            acc[mi][ni] = (f32x4){0.f, 0.f, 0.f, 0.f};

#pragma unroll
    for (int j = 0; j < 4; j++) {
        const int kk   = kh * 4 + j;
        const int slot = kk * 4 + (lane >> 4);
        short8 a[2], b[2];
#pragma unroll
        for (int mi = 0; mi < 2; mi++) {
            const int r = wr + mi * 16 + (lane & 15);
            a[mi] = *(const short8*)(As + r * F_DIM + ((slot ^ (r & 7)) << 3));
        }
#pragma unroll
        for (int ni = 0; ni < 2; ni++) {
            const int r = wc + ni * 16 + (lane & 15);
            b[ni] = *(const short8*)(Bs + r * F_DIM + ((slot ^ (r & 7)) << 3));
        }
#pragma unroll
        for (int mi = 0; mi < 2; mi++)
#pragma unroll
            for (int ni = 0; ni < 2; ni++)
                acc[mi][ni] = __builtin_amdgcn_mfma_f32_16x16x32_bf16(
                    a[mi], b[ni], acc[mi][ni], 0, 0, 0);
    }

    // ---------------- Split-K combine via LDS (reuse As) ----------------
    // Per (group g=kh-1, quad): 64 lanes x 64B. Slot s (int4) of lane l at
    // byte l*64 + ((s ^ ((l>>1)&3))*16): balanced across banks at the
    // structural b128 throughput floor.
    __syncthreads();  // all phase-2 ds_reads of As done before aliasing
    float* red = (float*)As;
    if (kh > 0) {
        const int g = kh - 1;
        float* base = red + (g * 4 + quad) * 1024 + lane * 16;
#pragma unroll
        for (int s = 0; s < 4; s++) {
            const int sw = s ^ ((lane >> 1) & 3);
            *(f32x4*)(base + sw * 4) = acc[s >> 1][s & 1];
        }
    }
    __syncthreads();
    if (kh == 0) {
#pragma unroll
        for (int g = 0; g < 3; g++) {
            const float* base = red + (g * 4 + quad) * 1024 + lane * 16;
#pragma unroll
            for (int s = 0; s < 4; s++) {
                const int sw = s ^ ((lane >> 1) & 3);
                f32x4 v = *(const f32x4*)(base + sw * 4);
#pragma unroll
                for (int j = 0; j < 4; j++) acc[s >> 1][s & 1][j] += v[j];
            }
        }

        // ---------------- Epilogue: out = 2*acc - |x|^2 - |m|^2 ----------
        // C/D layout: col = lane&15, row = (lane>>4)*4 + j.
        float xn[2][4];
#pragma unroll
        for (int mi = 0; mi < 2; mi++)
#pragma unroll
            for (int j = 0; j < 4; j++)
                xn[mi][j] = xn_s[wr + mi * 16 + (lane >> 4) * 4 + j];

#pragma unroll
        for (int ni = 0; ni < 2; ni++) {
            const int cl = wc + ni * 16 + (lane & 15);
            const int c  = colBase + cl;
            const float mn = mn_s[cl];
#pragma unroll
            for (int mi = 0; mi < 2; mi++) {
                const int rbase = rowBase + wr + mi * 16 + (lane >> 4) * 4;
#pragma unroll
                for (int j = 0; j < 4; j++)
                    out[(size_t)(rbase + j) * C_ROWS + c] =
                        2.0f * acc[mi][ni][j] - xn[mi][j] - mn;
            }
        }
    }
}

extern "C" void kernel_launch(void* const* d_in, const int* in_sizes, int n_in,
                              void* d_out, int out_size, void* d_ws, size_t ws_size,
                              hipStream_t stream) {
    const float* x     = (const float*)d_in[0];
    const float* means = (const float*)d_in[1];
    float* out = (float*)d_out;
    ncm_fused<<<256, 1024, 0, stream>>>(x, means, out);
}